// Round 10
// baseline (302.729 us; speedup 1.0000x reference)
//
#include <hip/hip_runtime.h>
#include <math.h>

// Problem constants: B=256, LMAX=512, NCOND=300, NHID=600
#define BB     256
#define LMAX   512
#define NCOND  300
#define NHID   600
#define NSEG   8          // 8 segments of 64 tokens
#define CHUNK  64
#define KPAD   320        // K padded to 10 chunks of 32 (k>=300 zero in W1T)
#define KLDS   328        // LDS row stride (elems): 656 B, 16B-aligned, 2-way bank alias = free
#define NKC    10         // KPAD/32
#define CTXB   157286400UL   // ctx bytes = 256*512*300*4

#define AS1 __attribute__((address_space(1)))
#define AS3 __attribute__((address_space(3)))

typedef short s16x8 __attribute__((ext_vector_type(8)));  // MFMA A/B frag (8 bf16)
typedef float f32x4 __attribute__((ext_vector_type(4)));  // MFMA accumulator

// fp32 -> bf16 round-to-nearest-even
__device__ inline unsigned short f2bf(float f) {
    unsigned int x = __float_as_uint(f);
    x += 0x7fffu + ((x >> 16) & 1u);
    return (unsigned short)(x >> 16);
}

// ---------------------------------------------------------------------------
// k0: build W1T bf16 in FRAGMENT-MAJOR layout (round-0 proven):
//   w1t[((ntile*NKC + kc)*64 + lane)*8 + j] = W1[kc*32+(lane>>4)*8+j][ntile*16+(lane&15)]
// ---------------------------------------------------------------------------
__global__ __launch_bounds__(256) void k0_w1t(const float* __restrict__ W1,
                                              unsigned short* __restrict__ w1t)
{
    const int t     = blockIdx.x * 256 + threadIdx.x;  // 0..25599
    const int lane  = t & 63;
    const int g     = t >> 6;                          // ntile*NKC + kc
    const int ntile = g / NKC;
    const int kc    = g - ntile * NKC;
    const int n     = ntile * 16 + (lane & 15);
    const int kbase = kc * 32 + (lane >> 4) * 8;
    union { unsigned short us[8]; s16x8 v8; } u;
#pragma unroll
    for (int j = 0; j < 8; ++j) {
        const int k = kbase + j;
        const float w = (n < NHID && k < NCOND) ? W1[(size_t)k * NHID + n] : 0.f;
        u.us[j] = f2bf(w);
    }
    *(s16x8*)(w1t + (size_t)t * 8) = u.v8;
}

// ---------------------------------------------------------------------------
// k1_dma_f32: r9's verified body with ONE staging change: the 38.4 KB
//   contiguous fp32 row-block is DMA'd into LDS via global_load_lds (38
//   fire-and-forget 1 KB wave-issues, no dest registers -> the compiler
//   CANNOT serialize them the way it collapsed r1/r8's register pipelines),
//   then the EXACT r9 convert loop runs LDS->LDS (guards intact -> bf16 tile
//   bit-identical to r9). K-loop / epilogue / planes unchanged.
//   LDS 38,912 + 20,992 = 59,904 B -> 2 blocks/CU, 8 waves/CU (r9 proved
//   occupancy beyond this is not the binding constraint).
//   Grid 1-D 8192: wg = b*32 + mh*16 + ch*8 + j, s=(j+b)&7 -> all 4 blocks
//   of a (b,s) are <=24 dispatches apart = same XCD (r8-verified win), and
//   dead segments rotate across XCDs.
// ---------------------------------------------------------------------------
__global__ __launch_bounds__(256, 2) void k1_dma_f32(
    const float* __restrict__ ctx, const int* __restrict__ lengths,
    const unsigned short* __restrict__ w1t, const float* __restrict__ b1,
    float* __restrict__ partial)   // two planes of [NSEG][BB][NHID]
{
    const int wg = blockIdx.x;              // 0..8191
    const int b  = wg >> 5;                 // batch
    const int mh = (wg >> 4) & 1;           // m-half: rows [mh*32, mh*32+32)
    const int ch = (wg >> 3) & 1;           // col-half
    const int s  = ((wg & 7) + b) & 7;      // rotated segment

    int count = lengths[b]; if (count < 1) count = 1;   // reference clamps lens >= 1
    const int l0 = s * CHUNK;
    if (l0 >= count) return;                            // dead segment: neither plane read
    const int valid = min(count - l0, CHUNK);           // rows of the FULL 64-row segment

    const int tid  = threadIdx.x;
    const int lane = tid & 63;
    const int wv   = tid >> 6;
    const int ln15 = lane & 15;
    const int kg   = lane >> 4;

    __shared__ __align__(16) char rawf[38912];                  // fp32 row-block (+pad)
    __shared__ __align__(16) unsigned short atile[32 * KLDS];   // 20,992 B bf16 tile

    // ---- stage 1: DMA the contiguous 32-row fp32 block (38,400 B, round up
    //      to 38 x 1 KB issues). Src clamped so the last block of ctx never
    //      reads past the buffer (tail garbage lands in unused LDS pad).
    const size_t B0 = ((size_t)b * LMAX + l0 + mh * 32) * (NCOND * 4);  // byte base
    const char* cbase = (const char*)ctx;
#pragma unroll
    for (int i = 0; i < 10; ++i) {
        const int idx = i * 4 + wv;           // wave-uniform
        if (idx < 38) {
            size_t sb = B0 + (size_t)idx * 1024;
            if (sb > CTXB - 1024) sb = CTXB - 1024;   // clamp (last ctx block only)
            __builtin_amdgcn_global_load_lds(
                (const AS1 void*)(cbase + sb + lane * 16),
                (AS3 void*)(rawf + idx * 1024), 16, 0, 0);
        }
    }

    // ---- prefetch kc=0 B-frags while the DMA drains (independent of LDS)
    const int ntile0 = ch * 20 + wv * 5;
    const unsigned short* bbase = w1t + ((size_t)ntile0 * NKC * 64 + lane) * 8;
    s16x8 bf[2][5];
#pragma unroll
    for (int nt = 0; nt < 5; ++nt) bf[0][nt] = *(const s16x8*)(bbase + nt * 5120);

    __syncthreads();    // vmcnt(0): DMA + prefetch complete

    // ---- stage 2: EXACT r9 convert loop, source = LDS raw instead of global.
    //      Tile contents bit-identical to r9 (rows>=valid and k>=300 zeroed).
#pragma unroll
    for (int p = 0; p < 5; ++p) {
        const int i  = p * 256 + tid;          // 0..1279
        const int r  = i / 40;                 // local row 0..31
        const int c8 = i - r * 40;             // 8-elem column chunk
        const int rg = mh * 32 + r;            // global row in segment
        union { unsigned short us[8]; s16x8 v8; } u;
        if (rg < valid && c8 < 38) {
            const char* src = rawf + r * 1200 + c8 * 32;
            const float4 v0 = *(const float4*)src;
            float4 v1 = make_float4(0.f, 0.f, 0.f, 0.f);
            if (c8 < 37) v1 = *(const float4*)(src + 16);
            u.us[0] = f2bf(v0.x); u.us[1] = f2bf(v0.y);
            u.us[2] = f2bf(v0.z); u.us[3] = f2bf(v0.w);
            u.us[4] = f2bf(v1.x); u.us[5] = f2bf(v1.y);
            u.us[6] = f2bf(v1.z); u.us[7] = f2bf(v1.w);
        } else {
#pragma unroll
            for (int j = 0; j < 8; ++j) u.us[j] = 0;
        }
        *(s16x8*)(atile + r * KLDS + c8 * 8) = u.v8;
    }
    __syncthreads();

    // ---- MFMA: wave wv owns cols [ch*320 + wv*80, +80) = 5 n-tiles x 2 m-tiles
    const unsigned short* arow = atile + ln15 * KLDS + kg * 8;

    f32x4 acc[5][2];
#pragma unroll
    for (int nt = 0; nt < 5; ++nt) {
        acc[nt][0] = (f32x4){0.f, 0.f, 0.f, 0.f};
        acc[nt][1] = (f32x4){0.f, 0.f, 0.f, 0.f};
    }

#pragma unroll
    for (int kc = 0; kc < NKC; ++kc) {
        const int cur = kc & 1, nxt = cur ^ 1;
        if (kc < NKC - 1) {
#pragma unroll
            for (int nt = 0; nt < 5; ++nt)
                bf[nxt][nt] = *(const s16x8*)(bbase + nt * 5120 + (kc + 1) * 512);
        }
        s16x8 af[2];
        af[0] = *(const s16x8*)(arow + kc * 32);
        af[1] = *(const s16x8*)(arow + 16 * KLDS + kc * 32);
#pragma unroll
        for (int nt = 0; nt < 5; ++nt) {
            acc[nt][0] = __builtin_amdgcn_mfma_f32_16x16x32_bf16(
                af[0], bf[cur][nt], acc[nt][0], 0, 0, 0);
            acc[nt][1] = __builtin_amdgcn_mfma_f32_16x16x32_bf16(
                af[1], bf[cur][nt], acc[nt][1], 0, 0, 0);
        }
    }

    // ---- epilogue: bias + ReLU, mask rows >= valid, reduce kg, write plane[mh]
    float* plane = partial + (size_t)mh * (NSEG * BB * NHID);
#pragma unroll
    for (int nt = 0; nt < 5; ++nt) {
        const int colg = ch * 320 + wv * 80 + nt * 16 + ln15;
        const float b1c = (colg < NHID) ? b1[colg] : 0.f;
        float ssum = 0.f;
#pragma unroll
        for (int j = 0; j < 2; ++j) {
            const int rbase = (mh * 2 + j) * 16 + kg * 4;   // global row base
#pragma unroll
            for (int r = 0; r < 4; ++r) {
                const float h = fmaxf(acc[nt][j][r] + b1c, 0.f);
                if (rbase + r < valid) ssum += h;
            }
        }
        ssum += __shfl_xor(ssum, 16, 64);
        ssum += __shfl_xor(ssum, 32, 64);
        if (kg == 0 && colg < NHID)
            plane[((size_t)s * BB + b) * NHID + colg] = ssum;
    }
}

// ---------------------------------------------------------------------------
// k2: 2 batches per block. Reduce BOTH mh planes over sp < ceil(len/64)
//     (others unwritten/poisoned -> skipped), /len, then
//     gate = sigmoid(pooled@Wa + ba); out = gate * x.   (r9 proven)
// ---------------------------------------------------------------------------
__global__ __launch_bounds__(640) void k2_gate(
    const float* __restrict__ x, const int* __restrict__ lengths,
    const float* __restrict__ partial, const float* __restrict__ Wa,
    const float* __restrict__ ba, float* __restrict__ out)
{
    const int b0  = blockIdx.x * 2;
    const int tid = threadIdx.x;

    __shared__ float pl[2][NHID];

    const float* plane1 = partial + (size_t)NSEG * BB * NHID;

    if (tid < NHID) {
#pragma unroll
        for (int bb = 0; bb < 2; ++bb) {
            int count = lengths[b0 + bb]; if (count < 1) count = 1;
            const int nch = (count + CHUNK - 1) >> 6;
            float ssum = 0.f;
            for (int sp = 0; sp < nch; ++sp) {
                const size_t off = ((size_t)sp * BB + (b0 + bb)) * NHID + tid;
                ssum += partial[off] + plane1[off];
            }
            pl[bb][tid] = ssum / (float)count;
        }
    }
    __syncthreads();

    if (tid < 2 * NCOND) {
        const int bb = tid / NCOND;        // 0 or 1
        const int n  = tid - bb * NCOND;   // lanes 0..299 and 300..599 share Wa addrs
        const int b  = b0 + bb;
        float a0 = ba[n], a1 = 0.f, a2 = 0.f, a3 = 0.f;
        const float4* p4 = (const float4*)pl[bb];
        for (int h4 = 0; h4 < 148; h4 += 4) {   // h = 0..591
            const float4 pv0 = p4[h4];
            const float4 pv1 = p4[h4 + 1];
            const float4 pv2 = p4[h4 + 2];
            const float4 pv3 = p4[h4 + 3];
            const int hb = h4 * 4;
            a0 = fmaf(pv0.x, Wa[(size_t)(hb +  0) * NCOND + n], a0);
            a0 = fmaf(pv0.y, Wa[(size_t)(hb +  1) * NCOND + n], a0);
            a0 = fmaf(pv0.z, Wa[(size_t)(hb +  2) * NCOND + n], a0);
            a0 = fmaf(pv0.w, Wa[(size_t)(hb +  3) * NCOND + n], a0);
            a1 = fmaf(pv1.x, Wa[(size_t)(hb +  4) * NCOND + n], a1);
            a1 = fmaf(pv1.y, Wa[(size_t)(hb +  5) * NCOND + n], a1);
            a1 = fmaf(pv1.z, Wa[(size_t)(hb +  6) * NCOND + n], a1);
            a1 = fmaf(pv1.w, Wa[(size_t)(hb +  7) * NCOND + n], a1);
            a2 = fmaf(pv2.x, Wa[(size_t)(hb +  8) * NCOND + n], a2);
            a2 = fmaf(pv2.y, Wa[(size_t)(hb +  9) * NCOND + n], a2);
            a2 = fmaf(pv2.z, Wa[(size_t)(hb + 10) * NCOND + n], a2);
            a2 = fmaf(pv2.w, Wa[(size_t)(hb + 11) * NCOND + n], a2);
            a3 = fmaf(pv3.x, Wa[(size_t)(hb + 12) * NCOND + n], a3);
            a3 = fmaf(pv3.y, Wa[(size_t)(hb + 13) * NCOND + n], a3);
            a3 = fmaf(pv3.z, Wa[(size_t)(hb + 14) * NCOND + n], a3);
            a3 = fmaf(pv3.w, Wa[(size_t)(hb + 15) * NCOND + n], a3);
        }
        {   // tail: h = 592..599
            const float4 pv0 = p4[148];
            const float4 pv1 = p4[149];
            a0 = fmaf(pv0.x, Wa[(size_t)592 * NCOND + n], a0);
            a0 = fmaf(pv0.y, Wa[(size_t)593 * NCOND + n], a0);
            a0 = fmaf(pv0.z, Wa[(size_t)594 * NCOND + n], a0);
            a0 = fmaf(pv0.w, Wa[(size_t)595 * NCOND + n], a0);
            a1 = fmaf(pv1.x, Wa[(size_t)596 * NCOND + n], a1);
            a1 = fmaf(pv1.y, Wa[(size_t)597 * NCOND + n], a1);
            a1 = fmaf(pv1.z, Wa[(size_t)598 * NCOND + n], a1);
            a1 = fmaf(pv1.w, Wa[(size_t)599 * NCOND + n], a1);
        }
        const float acc  = (a0 + a1) + (a2 + a3);
        const float gate = 1.0f / (1.0f + expf(-acc));
        out[(size_t)b * NCOND + n] = gate * x[(size_t)b * NCOND + n];
    }
}

extern "C" void kernel_launch(void* const* d_in, const int* in_sizes, int n_in,
                              void* d_out, int out_size, void* d_ws, size_t ws_size,
                              hipStream_t stream)
{
    // setup_inputs() order: x, context, lengths, W1, b1, Wa, ba
    const float* x       = (const float*)d_in[0];
    const float* ctx     = (const float*)d_in[1];
    const int*   lengths = (const int*)  d_in[2];
    const float* W1      = (const float*)d_in[3];
    const float* b1      = (const float*)d_in[4];
    const float* Wa      = (const float*)d_in[5];
    const float* ba      = (const float*)d_in[6];
    float*       out     = (float*)d_out;

    // ws layout: [w1t 409,600 B][partial 2 planes x 4,915,200 B]
    unsigned short* w1t     = (unsigned short*)d_ws;
    float*          partial = (float*)((char*)d_ws + 409600);

    k0_w1t<<<100, 256, 0, stream>>>(W1, w1t);
    k1_dma_f32<<<BB * NSEG * 4, 256, 0, stream>>>(ctx, lengths, w1t, b1, partial);
    k2_gate<<<BB / 2, 640, 0, stream>>>(x, lengths, partial, Wa, ba, out);
}

// Round 11
// 283.405 us; speedup vs baseline: 1.0682x; 1.0682x over previous
//
#include <hip/hip_runtime.h>
#include <math.h>

// Problem constants: B=256, LMAX=512, NCOND=300, NHID=600
#define BB     256
#define LMAX   512
#define NCOND  300
#define NHID   600
#define NSEG   8          // 8 segments of 64 tokens
#define CHUNK  64
#define KPAD   320        // K padded to 10 chunks of 32 (k>=300 zero in W1T)
#define KLDS   328        // LDS row stride (elems): 656 B, 16B-aligned, 2-way bank alias = free
#define NKC    10         // KPAD/32
#define CTXB   157286400UL   // ctx bytes = 256*512*300*4

#define AS1 __attribute__((address_space(1)))
#define AS3 __attribute__((address_space(3)))

typedef short s16x8 __attribute__((ext_vector_type(8)));  // MFMA A/B frag (8 bf16)
typedef float f32x4 __attribute__((ext_vector_type(4)));  // MFMA accumulator

// fp32 -> bf16 round-to-nearest-even
__device__ inline unsigned short f2bf(float f) {
    unsigned int x = __float_as_uint(f);
    x += 0x7fffu + ((x >> 16) & 1u);
    return (unsigned short)(x >> 16);
}

// ---------------------------------------------------------------------------
// k0: build W1T bf16 in FRAGMENT-MAJOR layout (round-0 proven).
// ---------------------------------------------------------------------------
__global__ __launch_bounds__(256) void k0_w1t(const float* __restrict__ W1,
                                              unsigned short* __restrict__ w1t)
{
    const int t     = blockIdx.x * 256 + threadIdx.x;  // 0..25599
    const int lane  = t & 63;
    const int g     = t >> 6;                          // ntile*NKC + kc
    const int ntile = g / NKC;
    const int kc    = g - ntile * NKC;
    const int n     = ntile * 16 + (lane & 15);
    const int kbase = kc * 32 + (lane >> 4) * 8;
    union { unsigned short us[8]; s16x8 v8; } u;
#pragma unroll
    for (int j = 0; j < 8; ++j) {
        const int k = kbase + j;
        const float w = (n < NHID && k < NCOND) ? W1[(size_t)k * NHID + n] : 0.f;
        u.us[j] = f2bf(w);
    }
    *(s16x8*)(w1t + (size_t)t * 8) = u.v8;
}

// ---------------------------------------------------------------------------
// k1_dma_u: r10's DMA front-end (FETCH 87->48.6 MB, verified) with the fp32
//   raw buffer and the bf16 tile UNIONED in ONE 38,912 B LDS allocation ->
//   4 blocks/CU (was 2), restoring cross-block phase overlap (r10's missing
//   ingredient: DMA of one block hides under K-loop of another).
//   Convert = LDS->reg->LDS, two passes with provably disjoint ranges:
//     pass1 (p=0,1): reads fp32 bytes <=15,392; writes bf16 bytes <=8,496
//     pass2 (p=2..4): reads fp32 bytes >=15,424; writes bf16 bytes in
//                     [7,872..20,976] (after a barrier)
//   bf16 writes of pass1 (<=8,496) never touch pass2's fp32 reads (>=15,424)
//   -> no extra barrier between C1 and B2. Register spike: 16/24 regs.
//   K-loop / epilogue / planes / grid mapping identical to r9/r10
//   (XCD ch-pairing + dead-segment rotation, mh planes).
// ---------------------------------------------------------------------------
__global__ __launch_bounds__(256, 4) void k1_dma_u(
    const float* __restrict__ ctx, const int* __restrict__ lengths,
    const unsigned short* __restrict__ w1t, const float* __restrict__ b1,
    float* __restrict__ partial)   // two planes of [NSEG][BB][NHID]
{
    const int wg = blockIdx.x;              // 0..8191
    const int b  = wg >> 5;                 // batch
    const int mh = (wg >> 4) & 1;           // m-half: rows [mh*32, mh*32+32)
    const int ch = (wg >> 3) & 1;           // col-half
    const int s  = ((wg & 7) + b) & 7;      // rotated segment

    int count = lengths[b]; if (count < 1) count = 1;   // reference clamps lens >= 1
    const int l0 = s * CHUNK;
    if (l0 >= count) return;                            // dead segment: neither plane read
    const int valid = min(count - l0, CHUNK);           // rows of the FULL 64-row segment

    const int tid  = threadIdx.x;
    const int lane = tid & 63;
    const int wv   = tid >> 6;
    const int ln15 = lane & 15;
    const int kg   = lane >> 4;

    // UNION: bytes [0,38400) = fp32 raw rows (stride 1200 B) during staging;
    //        bytes [0,20992) = bf16 tile (stride 656 B) afterwards.
    __shared__ __align__(16) char smem[38912];
    unsigned short* atile = (unsigned short*)smem;

    // ---- stage A: DMA the contiguous 32-row fp32 block (38 x 1 KB issues,
    //      fire-and-forget; covers the union buffer exactly). Tail-clamped.
    const size_t B0 = ((size_t)b * LMAX + l0 + mh * 32) * (NCOND * 4);  // byte base
    const char* cbase = (const char*)ctx;
#pragma unroll
    for (int i = 0; i < 10; ++i) {
        const int idx = i * 4 + wv;           // wave-uniform
        if (idx < 38) {
            size_t sb = B0 + (size_t)idx * 1024;
            if (sb > CTXB - 1024) sb = CTXB - 1024;   // clamp (last ctx block only)
            __builtin_amdgcn_global_load_lds(
                (const AS1 void*)(cbase + sb + lane * 16),
                (AS3 void*)(smem + idx * 1024), 16, 0, 0);
        }
    }

    // ---- prefetch kc=0 B-frags while the DMA drains (independent of LDS)
    const int ntile0 = ch * 20 + wv * 5;
    const unsigned short* bbase = w1t + ((size_t)ntile0 * NKC * 64 + lane) * 8;
    s16x8 bf[2][5];
#pragma unroll
    for (int nt = 0; nt < 5; ++nt) bf[0][nt] = *(const s16x8*)(bbase + nt * 5120);

    __syncthreads();    // BAR1: DMA complete (vmcnt 0)

    // helper lambdas kept macro-style for static indexing (rule #20)
#define STG_R(p)  (( (p) * 256 + tid) / 40)
#define STG_C(p)  (( (p) * 256 + tid) - STG_R(p) * 40)

    // ---- B1: read p=0,1 (fp32 bytes <= 15,392), unguarded (garbage discarded
    //      at write time by the same guards as r9/r10 -> tile bit-identical)
    float4 s0a, s0b, s1a, s1b;
    {
        const char* src0 = smem + STG_R(0) * 1200 + STG_C(0) * 32;
        s0a = *(const float4*)src0;  s0b = *(const float4*)(src0 + 16);
        const char* src1 = smem + STG_R(1) * 1200 + STG_C(1) * 32;
        s1a = *(const float4*)src1;  s1b = *(const float4*)(src1 + 16);
    }
    __syncthreads();    // BAR2: all B1 reads done before C1 overwrites

#define CVT_WRITE(p, va, vb) { \
    const int r_  = STG_R(p); \
    const int c8_ = STG_C(p); \
    const int rg_ = mh * 32 + r_; \
    const bool g0 = (rg_ < valid) && (c8_ < 38); \
    const bool g1 = (rg_ < valid) && (c8_ < 37); \
    union { unsigned short us[8]; s16x8 v8; } u_; \
    u_.us[0] = g0 ? f2bf(va.x) : 0; u_.us[1] = g0 ? f2bf(va.y) : 0; \
    u_.us[2] = g0 ? f2bf(va.z) : 0; u_.us[3] = g0 ? f2bf(va.w) : 0; \
    u_.us[4] = g1 ? f2bf(vb.x) : 0; u_.us[5] = g1 ? f2bf(vb.y) : 0; \
    u_.us[6] = g1 ? f2bf(vb.z) : 0; u_.us[7] = g1 ? f2bf(vb.w) : 0; \
    *(s16x8*)(atile + r_ * KLDS + c8_ * 8) = u_.v8; }

    // ---- C1: write p=0,1 (bf16 bytes <= 8,496)
    CVT_WRITE(0, s0a, s0b)
    CVT_WRITE(1, s1a, s1b)

    // ---- B2: read p=2,3,4 (fp32 bytes >= 15,424 -- disjoint from C1 writes)
    float4 s2a, s2b, s3a, s3b, s4a, s4b;
    {
        const char* src2 = smem + STG_R(2) * 1200 + STG_C(2) * 32;
        s2a = *(const float4*)src2;  s2b = *(const float4*)(src2 + 16);
        const char* src3 = smem + STG_R(3) * 1200 + STG_C(3) * 32;
        s3a = *(const float4*)src3;  s3b = *(const float4*)(src3 + 16);
        const char* src4 = smem + STG_R(4) * 1200 + STG_C(4) * 32;
        s4a = *(const float4*)src4;  s4b = *(const float4*)(src4 + 16);
    }
    __syncthreads();    // BAR3: all B2 reads done before C2 overwrites

    // ---- C2: write p=2,3,4
    CVT_WRITE(2, s2a, s2b)
    CVT_WRITE(3, s3a, s3b)
    CVT_WRITE(4, s4a, s4b)
#undef CVT_WRITE
#undef STG_R
#undef STG_C

    __syncthreads();    // BAR4: tile complete

    // ---- MFMA: wave wv owns cols [ch*320 + wv*80, +80) = 5 n-tiles x 2 m-tiles
    const unsigned short* arow = atile + ln15 * KLDS + kg * 8;

    f32x4 acc[5][2];
#pragma unroll
    for (int nt = 0; nt < 5; ++nt) {
        acc[nt][0] = (f32x4){0.f, 0.f, 0.f, 0.f};
        acc[nt][1] = (f32x4){0.f, 0.f, 0.f, 0.f};
    }

#pragma unroll
    for (int kc = 0; kc < NKC; ++kc) {
        const int cur = kc & 1, nxt = cur ^ 1;
        if (kc < NKC - 1) {
#pragma unroll
            for (int nt = 0; nt < 5; ++nt)
                bf[nxt][nt] = *(const s16x8*)(bbase + nt * 5120 + (kc + 1) * 512);
        }
        s16x8 af[2];
        af[0] = *(const s16x8*)(arow + kc * 32);
        af[1] = *(const s16x8*)(arow + 16 * KLDS + kc * 32);
#pragma unroll
        for (int nt = 0; nt < 5; ++nt) {
            acc[nt][0] = __builtin_amdgcn_mfma_f32_16x16x32_bf16(
                af[0], bf[cur][nt], acc[nt][0], 0, 0, 0);
            acc[nt][1] = __builtin_amdgcn_mfma_f32_16x16x32_bf16(
                af[1], bf[cur][nt], acc[nt][1], 0, 0, 0);
        }
    }

    // ---- epilogue: bias + ReLU, mask rows >= valid, reduce kg, write plane[mh]
    float* plane = partial + (size_t)mh * (NSEG * BB * NHID);
#pragma unroll
    for (int nt = 0; nt < 5; ++nt) {
        const int colg = ch * 320 + wv * 80 + nt * 16 + ln15;
        const float b1c = (colg < NHID) ? b1[colg] : 0.f;
        float ssum = 0.f;
#pragma unroll
        for (int j = 0; j < 2; ++j) {
            const int rbase = (mh * 2 + j) * 16 + kg * 4;   // global row base
#pragma unroll
            for (int r = 0; r < 4; ++r) {
                const float h = fmaxf(acc[nt][j][r] + b1c, 0.f);
                if (rbase + r < valid) ssum += h;
            }
        }
        ssum += __shfl_xor(ssum, 16, 64);
        ssum += __shfl_xor(ssum, 32, 64);
        if (kg == 0 && colg < NHID)
            plane[((size_t)s * BB + b) * NHID + colg] = ssum;
    }
}

// ---------------------------------------------------------------------------
// k2: 2 batches per block. Reduce BOTH mh planes over sp < ceil(len/64)
//     (others unwritten/poisoned -> skipped), /len, then
//     gate = sigmoid(pooled@Wa + ba); out = gate * x.   (r9 proven)
// ---------------------------------------------------------------------------
__global__ __launch_bounds__(640) void k2_gate(
    const float* __restrict__ x, const int* __restrict__ lengths,
    const float* __restrict__ partial, const float* __restrict__ Wa,
    const float* __restrict__ ba, float* __restrict__ out)
{
    const int b0  = blockIdx.x * 2;
    const int tid = threadIdx.x;

    __shared__ float pl[2][NHID];

    const float* plane1 = partial + (size_t)NSEG * BB * NHID;

    if (tid < NHID) {
#pragma unroll
        for (int bb = 0; bb < 2; ++bb) {
            int count = lengths[b0 + bb]; if (count < 1) count = 1;
            const int nch = (count + CHUNK - 1) >> 6;
            float ssum = 0.f;
            for (int sp = 0; sp < nch; ++sp) {
                const size_t off = ((size_t)sp * BB + (b0 + bb)) * NHID + tid;
                ssum += partial[off] + plane1[off];
            }
            pl[bb][tid] = ssum / (float)count;
        }
    }
    __syncthreads();

    if (tid < 2 * NCOND) {
        const int bb = tid / NCOND;        // 0 or 1
        const int n  = tid - bb * NCOND;   // lanes 0..299 and 300..599 share Wa addrs
        const int b  = b0 + bb;
        float a0 = ba[n], a1 = 0.f, a2 = 0.f, a3 = 0.f;
        const float4* p4 = (const float4*)pl[bb];
        for (int h4 = 0; h4 < 148; h4 += 4) {   // h = 0..591
            const float4 pv0 = p4[h4];
            const float4 pv1 = p4[h4 + 1];
            const float4 pv2 = p4[h4 + 2];
            const float4 pv3 = p4[h4 + 3];
            const int hb = h4 * 4;
            a0 = fmaf(pv0.x, Wa[(size_t)(hb +  0) * NCOND + n], a0);
            a0 = fmaf(pv0.y, Wa[(size_t)(hb +  1) * NCOND + n], a0);
            a0 = fmaf(pv0.z, Wa[(size_t)(hb +  2) * NCOND + n], a0);
            a0 = fmaf(pv0.w, Wa[(size_t)(hb +  3) * NCOND + n], a0);
            a1 = fmaf(pv1.x, Wa[(size_t)(hb +  4) * NCOND + n], a1);
            a1 = fmaf(pv1.y, Wa[(size_t)(hb +  5) * NCOND + n], a1);
            a1 = fmaf(pv1.z, Wa[(size_t)(hb +  6) * NCOND + n], a1);
            a1 = fmaf(pv1.w, Wa[(size_t)(hb +  7) * NCOND + n], a1);
            a2 = fmaf(pv2.x, Wa[(size_t)(hb +  8) * NCOND + n], a2);
            a2 = fmaf(pv2.y, Wa[(size_t)(hb +  9) * NCOND + n], a2);
            a2 = fmaf(pv2.z, Wa[(size_t)(hb + 10) * NCOND + n], a2);
            a2 = fmaf(pv2.w, Wa[(size_t)(hb + 11) * NCOND + n], a2);
            a3 = fmaf(pv3.x, Wa[(size_t)(hb + 12) * NCOND + n], a3);
            a3 = fmaf(pv3.y, Wa[(size_t)(hb + 13) * NCOND + n], a3);
            a3 = fmaf(pv3.z, Wa[(size_t)(hb + 14) * NCOND + n], a3);
            a3 = fmaf(pv3.w, Wa[(size_t)(hb + 15) * NCOND + n], a3);
        }
        {   // tail: h = 592..599
            const float4 pv0 = p4[148];
            const float4 pv1 = p4[149];
            a0 = fmaf(pv0.x, Wa[(size_t)592 * NCOND + n], a0);
            a0 = fmaf(pv0.y, Wa[(size_t)593 * NCOND + n], a0);
            a0 = fmaf(pv0.z, Wa[(size_t)594 * NCOND + n], a0);
            a0 = fmaf(pv0.w, Wa[(size_t)595 * NCOND + n], a0);
            a1 = fmaf(pv1.x, Wa[(size_t)596 * NCOND + n], a1);
            a1 = fmaf(pv1.y, Wa[(size_t)597 * NCOND + n], a1);
            a1 = fmaf(pv1.z, Wa[(size_t)598 * NCOND + n], a1);
            a1 = fmaf(pv1.w, Wa[(size_t)599 * NCOND + n], a1);
        }
        const float acc  = (a0 + a1) + (a2 + a3);
        const float gate = 1.0f / (1.0f + expf(-acc));
        out[(size_t)b * NCOND + n] = gate * x[(size_t)b * NCOND + n];
    }
}

extern "C" void kernel_launch(void* const* d_in, const int* in_sizes, int n_in,
                              void* d_out, int out_size, void* d_ws, size_t ws_size,
                              hipStream_t stream)
{
    // setup_inputs() order: x, context, lengths, W1, b1, Wa, ba
    const float* x       = (const float*)d_in[0];
    const float* ctx     = (const float*)d_in[1];
    const int*   lengths = (const int*)  d_in[2];
    const float* W1      = (const float*)d_in[3];
    const float* b1      = (const float*)d_in[4];
    const float* Wa      = (const float*)d_in[5];
    const float* ba      = (const float*)d_in[6];
    float*       out     = (float*)d_out;

    // ws layout: [w1t 409,600 B][partial 2 planes x 4,915,200 B]
    unsigned short* w1t     = (unsigned short*)d_ws;
    float*          partial = (float*)((char*)d_ws + 409600);

    k0_w1t<<<100, 256, 0, stream>>>(W1, w1t);
    k1_dma_u<<<BB * NSEG * 4, 256, 0, stream>>>(ctx, lengths, w1t, b1, partial);
    k2_gate<<<BB / 2, 640, 0, stream>>>(x, lengths, partial, Wa, ba, out);
}